// Round 12
// baseline (342.326 us; speedup 1.0000x reference)
//
#include <hip/hip_runtime.h>

#define NN 20000
#define NE 640000
#define DIM 128
#define ND (NN * DIM)

typedef float f32x4 __attribute__((ext_vector_type(4)));
typedef __bf16 bf16x8 __attribute__((ext_vector_type(8)));
typedef unsigned int u32;
typedef unsigned short u16;
typedef u32 u32x2 __attribute__((ext_vector_type(2)));

// XOR-swizzle for [rows][128] bf16 LDS tiles read as ds_read_b128 (G4 fix).
__device__ __forceinline__ int swz(int r, int c) {
  return r * DIM + (c ^ ((r & 7) << 3));
}
// sigma-stash addressing (u32 words, [64][128]): rotate cols by 8 per 4-row
// group -> exactly 2 lanes/bank on both the epilogue write and reduce read.
__device__ __forceinline__ int sgaddr(int row, int col) {
  return row * DIM + ((col + ((row & 12) << 1)) & 127);
}
// pack two f32 (truncating ->bf16) into one u32: lo16=bf16(a), hi16=bf16(b)
__device__ __forceinline__ u32 pk_bf16(float a, float b) {
  return __builtin_amdgcn_perm(__float_as_uint(b), __float_as_uint(a), 0x07060302u);
}
__device__ __forceinline__ float bf16_lo(u32 w) { return __uint_as_float(w << 16); }
__device__ __forceinline__ float bf16_hi(u32 w) { return __uint_as_float(w & 0xffff0000u); }
__device__ __forceinline__ float b2f(u16 v) { return __uint_as_float(((u32)v) << 16); }

// ---------------------------------------------------------------------------
// prep_hist: blocks [0,2500): histogram of dst. [2500,2756): wbf=[Wa,Wb,Wd,
// We] bf16 row-major (+BN fold). [2756,2764): wcp = Wc in MFMA frag order.
// ---------------------------------------------------------------------------
__global__ void prep_hist(const int* __restrict__ dst, int* __restrict__ cur,
                          const float* __restrict__ Wa, const float* __restrict__ Wb,
                          const float* __restrict__ Wd, const float* __restrict__ We,
                          const float* __restrict__ Wc, __bf16* __restrict__ wbf,
                          __bf16* __restrict__ wcp,
                          const float* __restrict__ gh, const float* __restrict__ bh,
                          const float* __restrict__ mh, const float* __restrict__ vh,
                          const float* __restrict__ ge, const float* __restrict__ be_,
                          const float* __restrict__ me, const float* __restrict__ ve,
                          float* __restrict__ bn) {
  int b = blockIdx.x;
  int tid = threadIdx.x;
  if (b < 2500) {                            // hist: 2500*256 == NE exactly
    atomicAdd(cur + dst[b * 256 + tid], 1);
    return;
  }
  b -= 2500;
  if (b < 256) {
    int g = b * 256 + tid;                   // < 65536
    int m = g >> 14;
    int off = g & 16383;
    const float* s = (m == 0) ? Wa : (m == 1) ? Wb : (m == 2) ? Wd : We;
    wbf[g] = (__bf16)s[off];
    if (g < DIM) {
      float sc = gh[g] * rsqrtf(vh[g] + 1e-5f);
      bn[g] = sc;
      bn[DIM + g] = bh[g] - mh[g] * sc;
    } else if (g < 2 * DIM) {
      int c = g - DIM;
      float sc = ge[c] * rsqrtf(ve[c] + 1e-5f);
      bn[2 * DIM + c] = sc;
      bn[3 * DIM + c] = be_[c] - me[c] * sc;
    }
  } else {
    int t2 = (b - 256) * 256 + tid;          // < 2048 chunks
    int lane = t2 & 63, nt = (t2 >> 6) & 7, ks = t2 >> 9;
    int lq = lane >> 4, lm = lane & 15;
    const float* srcp = Wc + (nt * 16 + lm) * DIM + ks * 32 + lq * 8;
    bf16x8 v;
#pragma unroll
    for (int j = 0; j < 8; ++j) v[j] = (__bf16)srcp[j];
    *(bf16x8*)(wcp + t2 * 8) = v;
  }
}

// ---------------------------------------------------------------------------
// scan (1 block, int4)
// ---------------------------------------------------------------------------
__global__ __launch_bounds__(1024) void scan20k(int* __restrict__ cur) {
  __shared__ int wsum[16];
  int tid = threadIdx.x, wid = tid >> 6, lane = tid & 63;
  int carry = 0;
  for (int base = 0; base < NN; base += 4096) {
    int idx = base + tid * 4;
    int4 v = {0, 0, 0, 0};
    if (idx < NN) v = *(const int4*)(cur + idx);
    int sum = v.x + v.y + v.z + v.w;
    int x = sum;
#pragma unroll
    for (int d = 1; d < 64; d <<= 1) {
      int y = __shfl_up(x, d, 64);
      if (lane >= d) x += y;
    }
    if (lane == 63) wsum[wid] = x;
    __syncthreads();
    if (tid < 16) {
      int s = wsum[tid];
#pragma unroll
      for (int d = 1; d < 16; d <<= 1) {
        int y = __shfl_up(s, d, 64);
        if (tid >= d) s += y;
      }
      wsum[tid] = s;
    }
    __syncthreads();
    int excl = carry + ((wid > 0) ? wsum[wid - 1] : 0) + x - sum;
    if (idx < NN) {
      int4 o;
      o.x = excl; o.y = excl + v.x; o.z = o.y + v.y; o.w = o.z + v.z;
      *(int4*)(cur + idx) = o;
    }
    carry += wsum[15];
    __syncthreads();
  }
}

// ---------------------------------------------------------------------------
// node_scatter (fused): blocks [0,1252) = node_gemm tiles (MFMA-heavy);
// blocks [1252,3752) = scatter (atomic-bound). Independent work overlaps.
// node m: 0 -> Ah(+ba), 1 -> Bhb(+bb), 2 -> Dhb(+bd+bc), 3 -> Ehb(+be)
// ---------------------------------------------------------------------------
#define NODE_BLOCKS 1252
__global__ __launch_bounds__(256) void node_scatter(
    const float* __restrict__ h, const __bf16* __restrict__ wbf,
    const float* __restrict__ ba, const float* __restrict__ bb,
    const float* __restrict__ bd, const float* __restrict__ be,
    const float* __restrict__ bc,
    float* __restrict__ Ah, __bf16* __restrict__ Bhb,
    __bf16* __restrict__ Dhb, __bf16* __restrict__ Ehb,
    const int* __restrict__ dst, int* __restrict__ cur,
    int* __restrict__ perm, int* __restrict__ dsts) {
  const int tid = threadIdx.x;
  if (blockIdx.x >= NODE_BLOCKS) {           // ---- scatter branch ----
    int e = (blockIdx.x - NODE_BLOCKS) * 256 + tid;
    int d = dst[e];
    int p = atomicAdd(cur + d, 1);
    perm[p] = e;
    dsts[p] = d;
    return;
  }
  // ---- node_gemm branch ----
  __shared__ __bf16 As[64 * DIM];
  __shared__ __bf16 Ws[DIM * DIM];
  const int m = blockIdx.x & 3;
  const int row0 = (blockIdx.x >> 2) * 64;

#pragma unroll
  for (int it = 0; it < 8; ++it) {
    int flat = it * 1024 + tid * 4;
    int r = flat >> 7, c = flat & 127;
    int grow = row0 + r;
    f32x4 v = (f32x4){0.f, 0.f, 0.f, 0.f};
    if (grow < NN) v = *(const f32x4*)(h + grow * DIM + c);
    u32x2 pk;
    pk[0] = pk_bf16(v[0], v[1]);
    pk[1] = pk_bf16(v[2], v[3]);
    *(u32x2*)(As + swz(r, c)) = pk;
  }
#pragma unroll
  for (int it = 0; it < 8; ++it) {
    int chunk = it * 256 + tid;
    int r = chunk >> 4, c0 = (chunk & 15) << 3;
    bf16x8 v = *(const bf16x8*)(wbf + m * DIM * DIM + (chunk << 3));
    *(bf16x8*)(Ws + swz(r, c0)) = v;
  }
  __syncthreads();

  const int wv = tid >> 6, lane = tid & 63;
  const int lq = lane >> 4, lm = lane & 15;

  f32x4 acc[8];
#pragma unroll
  for (int i = 0; i < 8; ++i) acc[i] = (f32x4){0.f, 0.f, 0.f, 0.f};
#pragma unroll
  for (int ks = 0; ks < 4; ++ks) {
    int k0 = ks * 32 + lq * 8;
    int ar = wv * 16 + lm;
    bf16x8 a = *(const bf16x8*)(As + swz(ar, k0));
#pragma unroll
    for (int nt = 0; nt < 8; ++nt) {
      int bcol = nt * 16 + lm;
      bf16x8 b = *(const bf16x8*)(Ws + swz(bcol, k0));
      acc[nt] = __builtin_amdgcn_mfma_f32_16x16x32_bf16(a, b, acc[nt], 0, 0, 0);
    }
  }

  const float* bias = (m == 0) ? ba : (m == 1) ? bb : (m == 2) ? bd : be;
#pragma unroll
  for (int nt = 0; nt < 8; ++nt) {
    int col = nt * 16 + lm;
    float bv = bias[col];
    if (m == 2) bv += bc[col];
#pragma unroll
    for (int r = 0; r < 4; ++r) {
      int grow = row0 + wv * 16 + lq * 4 + r;
      if (grow < NN) {
        float val = acc[nt][r] + bv;
        if (m == 0) Ah[grow * DIM + col] = val;
        else if (m == 1) Bhb[grow * DIM + col] = (__bf16)val;
        else if (m == 2) Dhb[grow * DIM + col] = (__bf16)val;
        else Ehb[grow * DIM + col] = (__bf16)val;
      }
    }
  }
}

// ---------------------------------------------------------------------------
// edge_gemm — r5 memory patterns with EXACTLY 32KB LDS (5 blocks/CU):
// s_perm/s_src parked in the union's dead upper 16KB during stage/GEMM,
// captured to registers before the sigma stash clobbers them; reduce reads
// dst runs from global dsts (256B/block, L1/L2-hot). launch_bounds(256,4)
// (NOT 5 — r9's forced bound spilled acc and tripled HBM traffic).
// ---------------------------------------------------------------------------
__global__ __launch_bounds__(256, 4) void edge_gemm(
    const float* __restrict__ e, const __bf16* __restrict__ wcp,
    const int* __restrict__ src,
    const int* __restrict__ perm, const int* __restrict__ dsts,
    const __bf16* __restrict__ Bhb, const __bf16* __restrict__ Dhb,
    const __bf16* __restrict__ Ehb,
    float* __restrict__ num, float* __restrict__ den,
    float* __restrict__ e_out, const float* __restrict__ bn) {
  __shared__ u32 smem[64 * DIM];             // exactly 32 KB
  __bf16* As = (__bf16*)smem;                // bytes [0, 16K): GEMM A-tile
  int* s_perm = (int*)(smem + 4096);         // bytes [16K,16.25K): dead in GEMM
  int* s_src  = s_perm + 64;                 // bytes [16.25K,16.5K)
  const int tid = threadIdx.x;
  const int e0 = blockIdx.x * 64;

  if (tid < 64) {
    int p = perm[e0 + tid];
    s_perm[tid] = p;
    s_src[tid] = src[p];
  }
  __syncthreads();

  // stage A: gathered rows e[perm], f32->bf16 via v_perm truncation
#pragma unroll
  for (int it = 0; it < 8; ++it) {
    int flat = it * 1024 + tid * 4;
    int r = flat >> 7, c = flat & 127;
    f32x4 v = __builtin_nontemporal_load(
        (const f32x4*)(e + (size_t)s_perm[r] * DIM + c));
    u32x2 pk;
    pk[0] = pk_bf16(v[0], v[1]);
    pk[1] = pk_bf16(v[2], v[3]);
    *(u32x2*)(As + swz(r, c)) = pk;
  }
  __syncthreads();

  const int wv = tid >> 6, lane = tid & 63;
  const int lq = lane >> 4, lm = lane & 15;

  f32x4 acc[8];
#pragma unroll
  for (int i = 0; i < 8; ++i) acc[i] = (f32x4){0.f, 0.f, 0.f, 0.f};
  const bf16x8* wp = (const bf16x8*)wcp;
#pragma unroll
  for (int ks = 0; ks < 4; ++ks) {
    int k0 = ks * 32 + lq * 8;
    int ar = wv * 16 + lm;
    bf16x8 a = *(const bf16x8*)(As + swz(ar, k0));
#pragma unroll
    for (int nt = 0; nt < 8; ++nt) {
      bf16x8 b = wp[(ks * 8 + nt) * 64 + lane];   // L1-resident packed Wc
      acc[nt] = __builtin_amdgcn_mfma_f32_16x16x32_bf16(a, b, acc[nt], 0, 0, 0);
    }
  }

  // capture this thread's row indices BEFORE sigma stash clobbers park area
  const int lrb = wv * 16 + lq * 4;
  int pR[4], sR[4], dR[4];
#pragma unroll
  for (int r4 = 0; r4 < 4; ++r4) {
    pR[r4] = s_perm[lrb + r4];
    sR[r4] = s_src[lrb + r4];
    dR[r4] = dsts[e0 + lrb + r4];
  }
  // hoist per-column BN constants (col = nt*16 + lm)
  float scv[8], shv[8];
#pragma unroll
  for (int nt = 0; nt < 8; ++nt) {
    scv[nt] = bn[2 * DIM + nt * 16 + lm];
    shv[nt] = bn[3 * DIM + nt * 16 + lm];
  }
  __syncthreads();   // As + park reads done before sigma stash reuse

  // epilogue: 4 rows/thread, hoisted base pointers, imm-offset element loads
#pragma unroll
  for (int r4 = 0; r4 < 4; ++r4) {
    const int lrow = lrb + r4;
    const u16* pD = (const u16*)Dhb + sR[r4] * DIM + lm;
    const u16* pE = (const u16*)Ehb + dR[r4] * DIM + lm;
    const u16* pB = (const u16*)Bhb + sR[r4] * DIM + lm;
    float* pO = e_out + (size_t)pR[r4] * DIM + lm;
#pragma unroll
    for (int nt = 0; nt < 8; ++nt) {
      float x = acc[nt][r4] + b2f(pD[nt * 16]) + b2f(pE[nt * 16]);
      float sig = __builtin_amdgcn_rcpf(1.0f + __expf(-x));
      float sb = sig * b2f(pB[nt * 16]);
      __builtin_nontemporal_store(fmaxf(scv[nt] * x + shv[nt], 0.0f),
                                  pO + nt * 16);
      smem[sgaddr(lrow, nt * 16 + lm)] = pk_bf16(sig, sb);
    }
  }
  __syncthreads();

  // segmented reduction: 2 threads/col, 32 sorted rows each; dst runs from
  // global dsts (same 256B per block, L1/L2-hot). Segments fully interior
  // to a half have a single writer anywhere -> plain store.
  {
    int col = tid >> 1;
    int r0 = (tid & 1) << 5;
    int4 dv8[8];
#pragma unroll
    for (int i = 0; i < 8; ++i)
      dv8[i] = *(const int4*)(dsts + e0 + r0 + i * 4);
    int dr[32];
#pragma unroll
    for (int i = 0; i < 8; ++i) {
      dr[i * 4] = dv8[i].x; dr[i * 4 + 1] = dv8[i].y;
      dr[i * 4 + 2] = dv8[i].z; dr[i * 4 + 3] = dv8[i].w;
    }
    float an = 0.f, ad = 0.f;
    int prev = dr[0];
    int seg_start = r0;
#pragma unroll 4
    for (int k = 0; k < 32; ++k) {
      int row = r0 + k;
      int d = dr[k];
      if (d != prev) {
        if (seg_start > r0) {            // exclusive segment
          num[prev * DIM + col] = an;
          den[prev * DIM + col] = ad;
        } else {
          atomicAdd(num + prev * DIM + col, an);
          atomicAdd(den + prev * DIM + col, ad);
        }
        an = 0.f; ad = 0.f; prev = d; seg_start = row;
      }
      u32 w = smem[sgaddr(row, col)];
      ad += bf16_lo(w);
      an += bf16_hi(w);
    }
    atomicAdd(num + prev * DIM + col, an);   // touches last row: always atomic
    atomicAdd(den + prev * DIM + col, ad);
  }
}

// ---------------------------------------------------------------------------
// final_h: h_out = relu(BN_h(Ah + num/(den+1e-6)))
// ---------------------------------------------------------------------------
__global__ void final_h(const float* __restrict__ Ah, const float* __restrict__ num,
                        const float* __restrict__ den, const float* __restrict__ bn,
                        float* __restrict__ h_out) {
  int g = blockIdx.x * blockDim.x + threadIdx.x;
  int idx = g * 4;
  int col = idx & (DIM - 1);
  f32x4 a = *(const f32x4*)(Ah + idx);
  f32x4 n = *(const f32x4*)(num + idx);
  f32x4 d = *(const f32x4*)(den + idx);
  f32x4 o;
#pragma unroll
  for (int j = 0; j < 4; ++j) {
    float hn = a[j] + n[j] * __builtin_amdgcn_rcpf(d[j] + 1e-6f);
    o[j] = fmaxf(bn[col + j] * hn + bn[DIM + col + j], 0.0f);
  }
  *(f32x4*)(h_out + idx) = o;
}

// ---------------------------------------------------------------------------
extern "C" void kernel_launch(void* const* d_in, const int* in_sizes, int n_in,
                              void* d_out, int out_size, void* d_ws, size_t ws_size,
                              hipStream_t stream) {
  (void)in_sizes; (void)n_in; (void)out_size; (void)ws_size;
  const float* h   = (const float*)d_in[0];
  const float* e   = (const float*)d_in[1];
  const int*   src = (const int*)d_in[2];
  const int*   dst = (const int*)d_in[3];
  const float* Wa  = (const float*)d_in[4];
  const float* ba  = (const float*)d_in[5];
  const float* Wb  = (const float*)d_in[6];
  const float* bb  = (const float*)d_in[7];
  const float* Wc  = (const float*)d_in[8];
  const float* bc  = (const float*)d_in[9];
  const float* Wd  = (const float*)d_in[10];
  const float* bd  = (const float*)d_in[11];
  const float* We  = (const float*)d_in[12];
  const float* be  = (const float*)d_in[13];
  const float* gamma_h = (const float*)d_in[14];
  const float* beta_h  = (const float*)d_in[15];
  const float* mean_h  = (const float*)d_in[16];
  const float* var_h   = (const float*)d_in[17];
  const float* gamma_e = (const float*)d_in[18];
  const float* beta_e  = (const float*)d_in[19];
  const float* mean_e  = (const float*)d_in[20];
  const float* var_e   = (const float*)d_in[21];

  float* ws  = (float*)d_ws;
  float* Ah  = ws;                                // ND f32
  float* num = Ah + ND;                           // ND f32
  float* den = num + ND;                          // ND f32
  __bf16* Bhb = (__bf16*)(den + ND);              // ND bf16
  __bf16* Dhb = Bhb + ND;                         // ND bf16 (holds Dh+bd+bc)
  __bf16* Ehb = Dhb + ND;                         // ND bf16
  __bf16* wbf = Ehb + ND;                         // 4*DIM*DIM bf16 (row-major)
  __bf16* wcp = wbf + 4 * DIM * DIM;              // DIM*DIM bf16 (frag order)
  float* bn  = (float*)(wcp + DIM * DIM);         // 4*DIM f32
  int*   cur = (int*)(bn + 4 * DIM);              // NN ints
  int*   perm = cur + NN;                         // NE ints
  int*   dsts = perm + NE;                        // NE ints (sorted dst)

  float* h_out = (float*)d_out;
  float* e_out = h_out + ND;

  hipMemsetAsync(num, 0, (size_t)2 * ND * sizeof(float), stream);
  hipMemsetAsync(cur, 0, (size_t)NN * sizeof(int), stream);
  prep_hist<<<2764, 256, 0, stream>>>(dst, cur, Wa, Wb, Wd, We, Wc, wbf, wcp,
                                      gamma_h, beta_h, mean_h, var_h,
                                      gamma_e, beta_e, mean_e, var_e, bn);
  scan20k<<<1, 1024, 0, stream>>>(cur);
  node_scatter<<<NODE_BLOCKS + NE / 256, 256, 0, stream>>>(
      h, wbf, ba, bb, bd, be, bc, Ah, Bhb, Dhb, Ehb, dst, cur, perm, dsts);
  edge_gemm<<<NE / 64, 256, 0, stream>>>(e, wcp, src, perm, dsts,
                                         Bhb, Dhb, Ehb, num, den, e_out, bn);
  final_h<<<ND / 4 / 256, 256, 0, stream>>>(Ah, num, den, bn, h_out);
}

// Round 13
// 317.179 us; speedup vs baseline: 1.0793x; 1.0793x over previous
//
#include <hip/hip_runtime.h>

#define NN 20000
#define NE 640000
#define DIM 128
#define ND (NN * DIM)

typedef float f32x4 __attribute__((ext_vector_type(4)));
typedef __bf16 bf16x8 __attribute__((ext_vector_type(8)));
typedef unsigned int u32;
typedef unsigned short u16;
typedef u32 u32x2 __attribute__((ext_vector_type(2)));

// XOR-swizzle for [rows][128] bf16 LDS tiles read as ds_read_b128 (G4 fix).
__device__ __forceinline__ int swz(int r, int c) {
  return r * DIM + (c ^ ((r & 7) << 3));
}
// sigma-stash addressing (u32 words, [64][128]): rotate cols by 8 per 4-row
// group -> exactly 2 lanes/bank on both the epilogue write and reduce read.
__device__ __forceinline__ int sgaddr(int row, int col) {
  return row * DIM + ((col + ((row & 12) << 1)) & 127);
}
// pack two f32 (truncating ->bf16) into one u32: lo16=bf16(a), hi16=bf16(b)
__device__ __forceinline__ u32 pk_bf16(float a, float b) {
  return __builtin_amdgcn_perm(__float_as_uint(b), __float_as_uint(a), 0x07060302u);
}
__device__ __forceinline__ float bf16_lo(u32 w) { return __uint_as_float(w << 16); }
__device__ __forceinline__ float bf16_hi(u32 w) { return __uint_as_float(w & 0xffff0000u); }
__device__ __forceinline__ float b2f(u16 v) { return __uint_as_float(((u32)v) << 16); }

// ---------------------------------------------------------------------------
// prep_hist: blocks [0,2500): histogram of dst. [2500,2756): wbf=[Wa,Wb,Wd,
// We] bf16 row-major (+BN fold). [2756,2764): wcp = Wc in MFMA frag order.
// ---------------------------------------------------------------------------
__global__ void prep_hist(const int* __restrict__ dst, int* __restrict__ cur,
                          const float* __restrict__ Wa, const float* __restrict__ Wb,
                          const float* __restrict__ Wd, const float* __restrict__ We,
                          const float* __restrict__ Wc, __bf16* __restrict__ wbf,
                          __bf16* __restrict__ wcp,
                          const float* __restrict__ gh, const float* __restrict__ bh,
                          const float* __restrict__ mh, const float* __restrict__ vh,
                          const float* __restrict__ ge, const float* __restrict__ be_,
                          const float* __restrict__ me, const float* __restrict__ ve,
                          float* __restrict__ bn) {
  int b = blockIdx.x;
  int tid = threadIdx.x;
  if (b < 2500) {                            // hist: 2500*256 == NE exactly
    atomicAdd(cur + dst[b * 256 + tid], 1);
    return;
  }
  b -= 2500;
  if (b < 256) {
    int g = b * 256 + tid;                   // < 65536
    int m = g >> 14;
    int off = g & 16383;
    const float* s = (m == 0) ? Wa : (m == 1) ? Wb : (m == 2) ? Wd : We;
    wbf[g] = (__bf16)s[off];
    if (g < DIM) {
      float sc = gh[g] * rsqrtf(vh[g] + 1e-5f);
      bn[g] = sc;
      bn[DIM + g] = bh[g] - mh[g] * sc;
    } else if (g < 2 * DIM) {
      int c = g - DIM;
      float sc = ge[c] * rsqrtf(ve[c] + 1e-5f);
      bn[2 * DIM + c] = sc;
      bn[3 * DIM + c] = be_[c] - me[c] * sc;
    }
  } else {
    int t2 = (b - 256) * 256 + tid;          // < 2048 chunks
    int lane = t2 & 63, nt = (t2 >> 6) & 7, ks = t2 >> 9;
    int lq = lane >> 4, lm = lane & 15;
    const float* srcp = Wc + (nt * 16 + lm) * DIM + ks * 32 + lq * 8;
    bf16x8 v;
#pragma unroll
    for (int j = 0; j < 8; ++j) v[j] = (__bf16)srcp[j];
    *(bf16x8*)(wcp + t2 * 8) = v;
  }
}

// ---------------------------------------------------------------------------
// scan (1 block, int4)
// ---------------------------------------------------------------------------
__global__ __launch_bounds__(1024) void scan20k(int* __restrict__ cur) {
  __shared__ int wsum[16];
  int tid = threadIdx.x, wid = tid >> 6, lane = tid & 63;
  int carry = 0;
  for (int base = 0; base < NN; base += 4096) {
    int idx = base + tid * 4;
    int4 v = {0, 0, 0, 0};
    if (idx < NN) v = *(const int4*)(cur + idx);
    int sum = v.x + v.y + v.z + v.w;
    int x = sum;
#pragma unroll
    for (int d = 1; d < 64; d <<= 1) {
      int y = __shfl_up(x, d, 64);
      if (lane >= d) x += y;
    }
    if (lane == 63) wsum[wid] = x;
    __syncthreads();
    if (tid < 16) {
      int s = wsum[tid];
#pragma unroll
      for (int d = 1; d < 16; d <<= 1) {
        int y = __shfl_up(s, d, 64);
        if (tid >= d) s += y;
      }
      wsum[tid] = s;
    }
    __syncthreads();
    int excl = carry + ((wid > 0) ? wsum[wid - 1] : 0) + x - sum;
    if (idx < NN) {
      int4 o;
      o.x = excl; o.y = excl + v.x; o.z = o.y + v.y; o.w = o.z + v.z;
      *(int4*)(cur + idx) = o;
    }
    carry += wsum[15];
    __syncthreads();
  }
}

// ---------------------------------------------------------------------------
// node_scatter (fused): blocks [0,1252) = node_gemm tiles (MFMA-heavy);
// blocks [1252,3752) = scatter (atomic-bound). Independent work overlaps.
// node m: 0 -> Ah(+ba), 1 -> Bhb(+bb), 2 -> Dhb(+bd+bc), 3 -> Ehb(+be)
// ---------------------------------------------------------------------------
#define NODE_BLOCKS 1252
__global__ __launch_bounds__(256) void node_scatter(
    const float* __restrict__ h, const __bf16* __restrict__ wbf,
    const float* __restrict__ ba, const float* __restrict__ bb,
    const float* __restrict__ bd, const float* __restrict__ be,
    const float* __restrict__ bc,
    float* __restrict__ Ah, __bf16* __restrict__ Bhb,
    __bf16* __restrict__ Dhb, __bf16* __restrict__ Ehb,
    const int* __restrict__ dst, int* __restrict__ cur,
    int* __restrict__ perm) {
  const int tid = threadIdx.x;
  if (blockIdx.x >= NODE_BLOCKS) {           // ---- scatter branch ----
    int e = (blockIdx.x - NODE_BLOCKS) * 256 + tid;
    int p = atomicAdd(cur + dst[e], 1);
    perm[p] = e;
    return;
  }
  // ---- node_gemm branch ----
  __shared__ __bf16 As[64 * DIM];
  __shared__ __bf16 Ws[DIM * DIM];
  const int m = blockIdx.x & 3;
  const int row0 = (blockIdx.x >> 2) * 64;

#pragma unroll
  for (int it = 0; it < 8; ++it) {
    int flat = it * 1024 + tid * 4;
    int r = flat >> 7, c = flat & 127;
    int grow = row0 + r;
    f32x4 v = (f32x4){0.f, 0.f, 0.f, 0.f};
    if (grow < NN) v = *(const f32x4*)(h + grow * DIM + c);
    u32x2 pk;
    pk[0] = pk_bf16(v[0], v[1]);
    pk[1] = pk_bf16(v[2], v[3]);
    *(u32x2*)(As + swz(r, c)) = pk;
  }
#pragma unroll
  for (int it = 0; it < 8; ++it) {
    int chunk = it * 256 + tid;
    int r = chunk >> 4, c0 = (chunk & 15) << 3;
    bf16x8 v = *(const bf16x8*)(wbf + m * DIM * DIM + (chunk << 3));
    *(bf16x8*)(Ws + swz(r, c0)) = v;
  }
  __syncthreads();

  const int wv = tid >> 6, lane = tid & 63;
  const int lq = lane >> 4, lm = lane & 15;

  f32x4 acc[8];
#pragma unroll
  for (int i = 0; i < 8; ++i) acc[i] = (f32x4){0.f, 0.f, 0.f, 0.f};
#pragma unroll
  for (int ks = 0; ks < 4; ++ks) {
    int k0 = ks * 32 + lq * 8;
    int ar = wv * 16 + lm;
    bf16x8 a = *(const bf16x8*)(As + swz(ar, k0));
#pragma unroll
    for (int nt = 0; nt < 8; ++nt) {
      int bcol = nt * 16 + lm;
      bf16x8 b = *(const bf16x8*)(Ws + swz(bcol, k0));
      acc[nt] = __builtin_amdgcn_mfma_f32_16x16x32_bf16(a, b, acc[nt], 0, 0, 0);
    }
  }

  const float* bias = (m == 0) ? ba : (m == 1) ? bb : (m == 2) ? bd : be;
#pragma unroll
  for (int nt = 0; nt < 8; ++nt) {
    int col = nt * 16 + lm;
    float bv = bias[col];
    if (m == 2) bv += bc[col];
#pragma unroll
    for (int r = 0; r < 4; ++r) {
      int grow = row0 + wv * 16 + lq * 4 + r;
      if (grow < NN) {
        float val = acc[nt][r] + bv;
        if (m == 0) Ah[grow * DIM + col] = val;
        else if (m == 1) Bhb[grow * DIM + col] = (__bf16)val;
        else if (m == 2) Dhb[grow * DIM + col] = (__bf16)val;
        else Ehb[grow * DIM + col] = (__bf16)val;
      }
    }
  }
}

// ---------------------------------------------------------------------------
// edge_gemm — ROUND-5 VERBATIM (measured 205 us): Ce = e[perm]@Wc.T;
// x = Ce + (Dh+bd+bc)[src] + Eh[dst]; e_out[perm] = relu(BN(x));
// epilogue: hoisted per-row base pointers + imm-offset element loads;
// sigma & sigma*B packed into one u32/elem in LDS; LDS-only segmented reduce.
// ---------------------------------------------------------------------------
union SmemU {
  __bf16 As[64 * DIM];   // 16KB, GEMM phase
  u32 sgp[64 * DIM];     // 32KB, packed (sigma, sigma*B), rotate-swizzled
};

__global__ __launch_bounds__(256, 4) void edge_gemm(
    const float* __restrict__ e, const __bf16* __restrict__ wcp,
    const int* __restrict__ src, const int* __restrict__ dst,
    const int* __restrict__ perm,
    const __bf16* __restrict__ Bhb, const __bf16* __restrict__ Dhb,
    const __bf16* __restrict__ Ehb,
    float* __restrict__ num, float* __restrict__ den,
    float* __restrict__ e_out, const float* __restrict__ bn) {
  __shared__ SmemU u;
  __shared__ int s_perm[64], s_src[64], s_dst[64];
  const int tid = threadIdx.x;
  const int e0 = blockIdx.x * 64;

  if (tid < 64) {
    int p = perm[e0 + tid];
    s_perm[tid] = p;
    s_src[tid] = src[p];
    s_dst[tid] = dst[p];
  }
  __syncthreads();

  // stage A: gathered rows e[perm], f32->bf16 via v_perm truncation
#pragma unroll
  for (int it = 0; it < 8; ++it) {
    int flat = it * 1024 + tid * 4;
    int r = flat >> 7, c = flat & 127;
    f32x4 v = __builtin_nontemporal_load(
        (const f32x4*)(e + (size_t)s_perm[r] * DIM + c));
    u32x2 pk;
    pk[0] = pk_bf16(v[0], v[1]);
    pk[1] = pk_bf16(v[2], v[3]);
    *(u32x2*)(u.As + swz(r, c)) = pk;
  }
  __syncthreads();

  const int wv = tid >> 6, lane = tid & 63;
  const int lq = lane >> 4, lm = lane & 15;

  f32x4 acc[8];
#pragma unroll
  for (int i = 0; i < 8; ++i) acc[i] = (f32x4){0.f, 0.f, 0.f, 0.f};
  const bf16x8* wp = (const bf16x8*)wcp;
#pragma unroll
  for (int ks = 0; ks < 4; ++ks) {
    int k0 = ks * 32 + lq * 8;
    int ar = wv * 16 + lm;
    bf16x8 a = *(const bf16x8*)(u.As + swz(ar, k0));
#pragma unroll
    for (int nt = 0; nt < 8; ++nt) {
      bf16x8 b = wp[(ks * 8 + nt) * 64 + lane];   // L1-resident packed Wc
      acc[nt] = __builtin_amdgcn_mfma_f32_16x16x32_bf16(a, b, acc[nt], 0, 0, 0);
    }
  }
  __syncthreads();   // As reads done before union reuse

  // hoist per-column BN constants (col = nt*16 + lm)
  float scv[8], shv[8];
#pragma unroll
  for (int nt = 0; nt < 8; ++nt) {
    scv[nt] = bn[2 * DIM + nt * 16 + lm];
    shv[nt] = bn[3 * DIM + nt * 16 + lm];
  }

  // epilogue: 4 rows/thread, hoisted base pointers, imm-offset element loads
#pragma unroll
  for (int r4 = 0; r4 < 4; ++r4) {
    int lrow = (tid >> 6) * 16 + lq * 4 + r4;
    int s = s_src[lrow];
    const u16* pD = (const u16*)Dhb + s * DIM + lm;
    const u16* pE = (const u16*)Ehb + s_dst[lrow] * DIM + lm;
    const u16* pB = (const u16*)Bhb + s * DIM + lm;
    float* pO = e_out + (size_t)s_perm[lrow] * DIM + lm;
#pragma unroll
    for (int nt = 0; nt < 8; ++nt) {
      float x = acc[nt][r4] + b2f(pD[nt * 16]) + b2f(pE[nt * 16]);
      float sig = __builtin_amdgcn_rcpf(1.0f + __expf(-x));
      float sb = sig * b2f(pB[nt * 16]);
      __builtin_nontemporal_store(fmaxf(scv[nt] * x + shv[nt], 0.0f),
                                  pO + nt * 16);
      u.sgp[sgaddr(lrow, nt * 16 + lm)] = pk_bf16(sig, sb);
    }
  }
  __syncthreads();

  // segmented reduction: 2 threads/col, 32 sorted rows each; segments fully
  // interior to a half have a single writer anywhere -> plain store.
  {
    int col = tid >> 1;
    int r0 = (tid & 1) << 5;
    float an = 0.f, ad = 0.f;
    int prev = s_dst[r0];
    int seg_start = r0;
#pragma unroll 4
    for (int k = 0; k < 32; ++k) {
      int row = r0 + k;
      int d = s_dst[row];
      if (d != prev) {
        if (seg_start > r0) {            // exclusive segment
          num[prev * DIM + col] = an;
          den[prev * DIM + col] = ad;
        } else {
          atomicAdd(num + prev * DIM + col, an);
          atomicAdd(den + prev * DIM + col, ad);
        }
        an = 0.f; ad = 0.f; prev = d; seg_start = row;
      }
      u32 w = u.sgp[sgaddr(row, col)];
      ad += bf16_lo(w);
      an += bf16_hi(w);
    }
    atomicAdd(num + prev * DIM + col, an);   // touches last row: always atomic
    atomicAdd(den + prev * DIM + col, ad);
  }
}

// ---------------------------------------------------------------------------
// final_h: h_out = relu(BN_h(Ah + num/(den+1e-6)))
// ---------------------------------------------------------------------------
__global__ void final_h(const float* __restrict__ Ah, const float* __restrict__ num,
                        const float* __restrict__ den, const float* __restrict__ bn,
                        float* __restrict__ h_out) {
  int g = blockIdx.x * blockDim.x + threadIdx.x;
  int idx = g * 4;
  int col = idx & (DIM - 1);
  f32x4 a = *(const f32x4*)(Ah + idx);
  f32x4 n = *(const f32x4*)(num + idx);
  f32x4 d = *(const f32x4*)(den + idx);
  f32x4 o;
#pragma unroll
  for (int j = 0; j < 4; ++j) {
    float hn = a[j] + n[j] * __builtin_amdgcn_rcpf(d[j] + 1e-6f);
    o[j] = fmaxf(bn[col + j] * hn + bn[DIM + col + j], 0.0f);
  }
  *(f32x4*)(h_out + idx) = o;
}

// ---------------------------------------------------------------------------
extern "C" void kernel_launch(void* const* d_in, const int* in_sizes, int n_in,
                              void* d_out, int out_size, void* d_ws, size_t ws_size,
                              hipStream_t stream) {
  (void)in_sizes; (void)n_in; (void)out_size; (void)ws_size;
  const float* h   = (const float*)d_in[0];
  const float* e   = (const float*)d_in[1];
  const int*   src = (const int*)d_in[2];
  const int*   dst = (const int*)d_in[3];
  const float* Wa  = (const float*)d_in[4];
  const float* ba  = (const float*)d_in[5];
  const float* Wb  = (const float*)d_in[6];
  const float* bb  = (const float*)d_in[7];
  const float* Wc  = (const float*)d_in[8];
  const float* bc  = (const float*)d_in[9];
  const float* Wd  = (const float*)d_in[10];
  const float* bd  = (const float*)d_in[11];
  const float* We  = (const float*)d_in[12];
  const float* be  = (const float*)d_in[13];
  const float* gamma_h = (const float*)d_in[14];
  const float* beta_h  = (const float*)d_in[15];
  const float* mean_h  = (const float*)d_in[16];
  const float* var_h   = (const float*)d_in[17];
  const float* gamma_e = (const float*)d_in[18];
  const float* beta_e  = (const float*)d_in[19];
  const float* mean_e  = (const float*)d_in[20];
  const float* var_e   = (const float*)d_in[21];

  float* ws  = (float*)d_ws;
  float* Ah  = ws;                                // ND f32
  float* num = Ah + ND;                           // ND f32
  float* den = num + ND;                          // ND f32
  __bf16* Bhb = (__bf16*)(den + ND);              // ND bf16
  __bf16* Dhb = Bhb + ND;                         // ND bf16 (holds Dh+bd+bc)
  __bf16* Ehb = Dhb + ND;                         // ND bf16
  __bf16* wbf = Ehb + ND;                         // 4*DIM*DIM bf16 (row-major)
  __bf16* wcp = wbf + 4 * DIM * DIM;              // DIM*DIM bf16 (frag order)
  float* bn  = (float*)(wcp + DIM * DIM);         // 4*DIM f32
  int*   cur = (int*)(bn + 4 * DIM);              // NN ints
  int*   perm = cur + NN;                         // NE ints

  float* h_out = (float*)d_out;
  float* e_out = h_out + ND;

  hipMemsetAsync(num, 0, (size_t)2 * ND * sizeof(float), stream);
  hipMemsetAsync(cur, 0, (size_t)NN * sizeof(int), stream);
  prep_hist<<<2764, 256, 0, stream>>>(dst, cur, Wa, Wb, Wd, We, Wc, wbf, wcp,
                                      gamma_h, beta_h, mean_h, var_h,
                                      gamma_e, beta_e, mean_e, var_e, bn);
  scan20k<<<1, 1024, 0, stream>>>(cur);
  node_scatter<<<NODE_BLOCKS + NE / 256, 256, 0, stream>>>(
      h, wbf, ba, bb, bd, be, bc, Ah, Bhb, Dhb, Ehb, dst, cur, perm);
  edge_gemm<<<NE / 64, 256, 0, stream>>>(e, wcp, src, dst, perm,
                                         Bhb, Dhb, Ehb, num, den, e_out, bn);
  final_h<<<ND / 4 / 256, 256, 0, stream>>>(Ah, num, den, bn, h_out);
}